// Round 12
// baseline (193.749 us; speedup 1.0000x reference)
//
#include <hip/hip_runtime.h>
#include <math.h>

#define NBX 168
#define NBY 480
#define NBL 6
#define PLANE (NBX * NBY)
#define MAPSZ (PLANE * NBL)
#define EXT 2
#define W 5
#define INV_SQRT2 0.70710678118654752440f
#define INV_CAP 0.0625f

/* ---- spatial tiling ---- */
#define TW 8                     /* tile width in x-bins  (168/8  = 21) */
#define TH 12                    /* tile height in y-bins (480/12 = 40) */
#define TX (NBX / TW)            /* 21 */
#define TY (NBY / TH)            /* 40 */
#define NT (TX * TY)             /* 840 tiles */
#define GPT (TW * TH * NBL)      /* 576 (cell,type) groups per tile */
#define NWAVES (GPT / 64)        /* 9 */
#define LTW (TW + 2 * EXT)       /* 12 */
#define LTH (TH + 2 * EXT)       /* 16 */
#define LTHP 17                  /* padded y stride (bank spread) */
#define TSTRIDE (LTW * LTHP)     /* 204 */
#define SLABP (NBL * TSTRIDE)    /* 1224 floats = 4.9 KB */
#define BATCH 640                /* items per LDS batch (>= CAP/SPLITD + slack) */
#define WSTR 13                  /* weight-record stride: coprime w/ 32 banks */
#define CAP 2048                 /* payload slots per tile (mean 1190, sd 35) */
#define WIN 1024                 /* items staged per LDS window in k_sort */
#define SPLITD 2                 /* half-tile split: round-granularity latency fix */

/* Branch-free erf, Abramowitz-Stegun 7.1.26 (|err| <= 1.5e-7, |x| <= 2.14 here). */
__device__ __forceinline__ float erf_fast(float x) {
    float ax = fabsf(x);
    float t = __builtin_amdgcn_rcpf(fmaf(0.3275911f, ax, 1.0f));
    float p = fmaf(1.061405429f, t, -1.453152027f);
    p = fmaf(p, t, 1.421413741f);
    p = fmaf(p, t, -0.284496736f);
    p = fmaf(p, t, 0.254829592f);
    p = p * t;
    float e = __expf(-ax * ax);
    float r = fmaf(-p, e, 1.0f);
    return copysignf(r, x);
}

/* 5 axis weights (zeroed for out-of-range bins). */
__device__ __forceinline__ void axis_w(float c, int nb, float* g) {
    int b0 = (int)floorf(c);
    float t0 = (float)(b0 - EXT) - c;
    float e[W + 1];
#pragma unroll
    for (int k = 0; k <= W; ++k) e[k] = erf_fast((t0 + (float)k) * INV_SQRT2);
#pragma unroll
    for (int j = 0; j < W; ++j) {
        int b = b0 - EXT + j;
        g[j] = (b >= 0 && b < nb) ? 0.5f * (e[j + 1] - e[j]) : 0.0f;
    }
}

__device__ __forceinline__ int tile_of_xy(float cx, float cy) {
    int bx = (int)floorf(cx); bx = bx < 0 ? 0 : (bx > NBX - 1 ? NBX - 1 : bx);
    int by = (int)floorf(cy); by = by < 0 ? 0 : (by > NBY - 1 ? NBY - 1 : by);
    return (bx / TW) * TY + (by / TH);
}

__device__ __forceinline__ int group_key(float4 p, int x0, int y0) {
    int bx = (int)floorf(p.x) - x0;
    int by = (int)floorf(p.y) - y0;
    bx = bx < 0 ? 0 : (bx > TW - 1 ? TW - 1 : bx);
    by = by < 0 ? 0 : (by > TH - 1 ? TH - 1 : by);
    return (bx * TH + by) * NBL + (__float_as_int(p.w) & 7);
}

/* Pass 1 (fused build+hist+scan+scatter): windowed LDS staging; one global
   reservation atomic per (block,window,tile); payloads land in fixed
   CAP-sized per-tile slots. */
__global__ void k_sort(const float* __restrict__ pos, const float* __restrict__ nsx,
                       const float* __restrict__ nsy, const int* __restrict__ idx,
                       const int* __restrict__ ltyp,
                       int* __restrict__ tileCount, float4* __restrict__ sorted,
                       int n, int Linst) {
    __shared__ float4 buf[WIN];
    __shared__ int cnt[NT];
    __shared__ int base[NT];
    int chunk = (Linst + gridDim.x - 1) / gridDim.x;
    int lo = blockIdx.x * chunk;
    int hi = lo + chunk; if (hi > Linst) hi = Linst;
    for (int w0 = lo; w0 < hi; w0 += WIN) {
        int wn = hi - w0; if (wn > WIN) wn = WIN;
        for (int t = threadIdx.x; t < NT; t += blockDim.x) cnt[t] = 0;
        __syncthreads();
        for (int j = threadIdx.x; j < wn; j += blockDim.x) {
            int i = w0 + j;
            int id = idx[i];
            float sx = nsx[id], sy = nsy[id];
            float cx = pos[id] + 0.5f * sx;
            float cy = pos[n + id] + 0.5f * sy;
            buf[j] = make_float4(cx, cy, sx * sy,
                                 __int_as_float((id << 3) | (ltyp[id] & 7)));
            atomicAdd(&cnt[tile_of_xy(cx, cy)], 1);
        }
        __syncthreads();
        for (int t = threadIdx.x; t < NT; t += blockDim.x) {
            base[t] = cnt[t] ? atomicAdd(&tileCount[t], cnt[t]) : 0;
            cnt[t] = 0;                 /* reuse as local cursor */
        }
        __syncthreads();
        for (int j = threadIdx.x; j < wn; j += blockDim.x) {
            float4 p = buf[j];
            int t = tile_of_xy(p.x, p.y);
            int r = base[t] + atomicAdd(&cnt[t], 1);
            if (r < CAP) sorted[(size_t)t * CAP + r] = p;   /* overflow guard */
        }
        __syncthreads();
    }
}

/* Pass 2 (fused subsort+demand), HALF-TILE blocks (round-latency fix):
   grid = NT*SPLITD; block handles its half of the tile's items (fits one
   BATCH), produces a PARTIAL slab at slabs[(tile*SPLITD)+half].
   Phase 1 balanced erf -> LDS weights; LDS counting sort (shuffle scan);
   phase 2 group-gather; 25-step barrier-phased race-free merge. */
__global__ __launch_bounds__(GPT) void k_demand3(const float4* __restrict__ sorted,
                                                 const int* __restrict__ tileCount,
                                                 float* __restrict__ slabs) {
    __shared__ float wbuf[BATCH * WSTR];
    __shared__ unsigned short keys[BATCH];
    __shared__ unsigned short order[BATCH];
    __shared__ int h[GPT];
    __shared__ int cur[GPT];
    __shared__ int wsum[NWAVES];
    __shared__ float slab[SLABP];
    int t = blockIdx.x / SPLITD, half = blockIdx.x % SPLITD;
    int tid = threadIdx.x;
    int cntT = tileCount[t]; if (cntT > CAP) cntT = CAP;
    int iLo = (cntT * half) / SPLITD;
    int iHi = (cntT * (half + 1)) / SPLITD;
    const float4* src = sorted + (size_t)t * CAP;
    int x0 = (t / TY) * TW, y0 = (t % TY) * TH;
    for (int s = tid; s < SLABP; s += GPT) slab[s] = 0.0f;
    int typ = tid % NBL, lc = tid / NBL;
    int lx = lc / TH, ly = lc % TH;
    int lane = tid & 63, wv = tid >> 6;
    float acc[W * W];
#pragma unroll
    for (int k = 0; k < W * W; ++k) acc[k] = 0.0f;

    for (int b = iLo; b < iHi; b += BATCH) {
        int cnt = iHi - b; if (cnt > BATCH) cnt = BATCH;
        h[tid] = 0;
        __syncthreads();
        /* phase 1: balanced erf + weight store + hist */
        for (int j = tid; j < cnt; j += GPT) {
            float4 p = src[b + j];
            int key = group_key(p, x0, y0);
            keys[j] = (unsigned short)key;
            float gx[W], gy[W];
            axis_w(p.x, NBX, gx);
            axis_w(p.y, NBY, gy);
            float* wr = &wbuf[j * WSTR];
#pragma unroll
            for (int k = 0; k < W; ++k) wr[k] = gx[k] * p.z;
#pragma unroll
            for (int k = 0; k < W; ++k) wr[W + k] = gy[k];
            atomicAdd(&h[key], 1);
        }
        __syncthreads();
        int v = h[tid];
        int sc = v;                         /* wave-level inclusive scan */
#pragma unroll
        for (int off = 1; off < 64; off <<= 1) {
            int u = __shfl_up(sc, off);
            if (lane >= off) sc += u;
        }
        if (lane == 63) wsum[wv] = sc;
        __syncthreads();
        int wbase = 0;
        for (int w2 = 0; w2 < wv; ++w2) wbase += wsum[w2];
        int myStart = wbase + sc - v;
        cur[tid] = myStart;
        __syncthreads();
        for (int j = tid; j < cnt; j += GPT) {
            int r = atomicAdd(&cur[(int)keys[j]], 1);
            order[r] = (unsigned short)j;
        }
        __syncthreads();
        /* phase 2: group-gather (divergent but cheap) */
        for (int k = 0; k < v; ++k) {
            const float* wr = &wbuf[(int)order[myStart + k] * WSTR];
            float gxp[W], gy[W];
#pragma unroll
            for (int q = 0; q < W; ++q) gxp[q] = wr[q];
#pragma unroll
            for (int q = 0; q < W; ++q) gy[q] = wr[W + q];
#pragma unroll
            for (int jx = 0; jx < W; ++jx) {
#pragma unroll
                for (int jy = 0; jy < W; ++jy)
                    acc[jx * W + jy] = fmaf(gxp[jx], gy[jy], acc[jx * W + jy]);
            }
        }
        __syncthreads();                    /* wbuf/h reuse fence */
    }

    int bse = typ * TSTRIDE + lx * LTHP + ly;
#pragma unroll
    for (int jx = 0; jx < W; ++jx) {
#pragma unroll
        for (int jy = 0; jy < W; ++jy) {
            __syncthreads();
            slab[bse + jx * LTHP + jy] += acc[jx * W + jy];   /* 0-add ok */
        }
    }
    __syncthreads();
    float* o = slabs + (size_t)blockIdx.x * SLABP;
    for (int s = tid; s < SLABP; s += GPT) o[s] = slab[s];
}

/* Pass 3 (fused compat+gather), HALF-TILE blocks: per half-tile block —
   assemble the tile's compat region in LDS from neighbor partial slabs
   (SPLITD per tile) + 6x6 fracture einsum, then one thread per INSTANCE
   over this block's half: 12 dense erfs, 25 LDS reads, dot, store. */
__global__ void k_out3(const float4* __restrict__ sorted,
                       const int* __restrict__ tileCount,
                       const float* __restrict__ slabs,
                       const int* __restrict__ frac,
                       float* __restrict__ out) {
    __shared__ float cc[SLABP];
    __shared__ float fr[NBL * NBL];
    int t = blockIdx.x / SPLITD, part = blockIdx.x % SPLITD;
    int x0 = (t / TY) * TW, y0 = (t % TY) * TH;
    if (threadIdx.x < NBL * NBL) fr[threadIdx.x] = (float)frac[threadIdx.x];
    __syncthreads();
    for (int s = threadIdx.x; s < LTW * LTH; s += blockDim.x) {
        int lxx = s / LTH, lyy = s % LTH;
        int x = x0 - EXT + lxx, y = y0 - EXT + lyy;
        float d[NBL] = {0, 0, 0, 0, 0, 0};
        if (x >= 0 && x < NBX && y >= 0 && y < NBY) {
            int tx = x / TW, xm = x % TW;
            int ty = y / TH, ym = y % TH;
            int ax0 = (xm < EXT && tx > 0) ? tx - 1 : tx;
            int ax1 = (xm >= TW - EXT && tx < TX - 1) ? tx + 1 : tx;
            int ay0 = (ym < EXT && ty > 0) ? ty - 1 : ty;
            int ay1 = (ym >= TH - EXT && ty < TY - 1) ? ty + 1 : ty;
            for (int ax = ax0; ax <= ax1; ++ax)
                for (int ay = ay0; ay <= ay1; ++ay) {
                    int lx = x - (ax * TW - EXT);
                    int ly = y - (ay * TH - EXT);
                    const float* sl = slabs
                        + (size_t)(ax * TY + ay) * SPLITD * SLABP
                        + lx * LTHP + ly;
#pragma unroll
                    for (int sp = 0; sp < SPLITD; ++sp) {
#pragma unroll
                        for (int l = 0; l < NBL; ++l)
                            d[l] += sl[sp * SLABP + l * TSTRIDE];
                    }
                }
        }
#pragma unroll
        for (int tt = 0; tt < NBL; ++tt) {
            float s2 = 0.0f;
#pragma unroll
            for (int l = 0; l < NBL; ++l) s2 += d[l] * fr[tt * NBL + l];
            cc[tt * TSTRIDE + lxx * LTHP + lyy] = s2;
        }
    }
    __syncthreads();
    int cntT = tileCount[t]; if (cntT > CAP) cntT = CAP;
    int iLo = (cntT * part) / SPLITD;
    int iHi = (cntT * (part + 1)) / SPLITD;
    const float4* src = sorted + (size_t)t * CAP;
    for (int j = iLo + threadIdx.x; j < iHi; j += blockDim.x) {
        float4 p = src[j];
        int packed = __float_as_int(p.w);
        int typ = packed & 7;
        float gxw[W], gyw[W];
        axis_w(p.x, NBX, gxw);
        axis_w(p.y, NBY, gyw);
        int lx = (int)floorf(p.x) - x0, ly = (int)floorf(p.y) - y0;
        lx = lx < 0 ? 0 : (lx > TW - 1 ? TW - 1 : lx);
        ly = ly < 0 ? 0 : (ly > TH - 1 ? TH - 1 : ly);
        int base = typ * TSTRIDE + lx * LTHP + ly;
        float sum = 0.0f;
#pragma unroll
        for (int jx = 0; jx < W; ++jx) {
            float row = 0.0f;
#pragma unroll
            for (int jy = 0; jy < W; ++jy)
                row = fmaf(gyw[jy], cc[base + jx * LTHP + jy], row);
            sum = fmaf(gxw[jx], row, sum);
        }
        out[packed >> 3] = sum * INV_CAP;
    }
}

/* ---------- fallback (atomic path) if ws_size is too small ---------- */
__device__ __forceinline__ void axis_frag_fb(float c, int nb, float* g, int* bc) {
    int b0 = (int)floorf(c);
    float t0 = (float)(b0 - EXT) - c;
    float e[W + 1];
#pragma unroll
    for (int k = 0; k <= W; ++k) e[k] = erf_fast((t0 + (float)k) * INV_SQRT2);
#pragma unroll
    for (int j = 0; j < W; ++j) {
        int b = b0 - EXT + j;
        g[j] = (b >= 0 && b < nb) ? 0.5f * (e[j + 1] - e[j]) : 0.0f;
        int bcl = b < 0 ? 0 : b;
        bc[j] = bcl > nb - 1 ? nb - 1 : bcl;
    }
}
__global__ void k_demand_atomic(const float* __restrict__ pos, const float* __restrict__ nsx,
                                const float* __restrict__ nsy, const int* __restrict__ idx,
                                const int* __restrict__ ltyp, float* __restrict__ dem,
                                int n, int Linst) {
    int i = blockIdx.x * blockDim.x + threadIdx.x;
    if (i >= Linst) return;
    int id = idx[i];
    float sx = nsx[id], sy = nsy[id];
    float cx = pos[id] + 0.5f * sx, cy = pos[n + id] + 0.5f * sy;
    float area = sx * sy;
    float gx[W], gy[W]; int bx[W], by[W];
    axis_frag_fb(cx, NBX, gx, bx);
    axis_frag_fb(cy, NBY, gy, by);
    float* plane = dem + ltyp[id] * PLANE;
#pragma unroll
    for (int jx = 0; jx < W; ++jx) {
        float wx = gx[jx] * area;
        if (wx == 0.0f) continue;
        float* row = plane + bx[jx] * NBY;
#pragma unroll
        for (int jy = 0; jy < W; ++jy) {
            float w = wx * gy[jy];
            if (w != 0.0f) atomicAdd(row + by[jy], w);
        }
    }
}
__global__ void k_compat_simple(const float* __restrict__ dem, const int* __restrict__ frac,
                                float* __restrict__ compat) {
    int xy = blockIdx.x * blockDim.x + threadIdx.x;
    if (xy >= PLANE) return;
    float d[NBL];
#pragma unroll
    for (int l = 0; l < NBL; ++l) d[l] = dem[l * PLANE + xy];
#pragma unroll
    for (int t = 0; t < NBL; ++t) {
        float s = 0.0f;
#pragma unroll
        for (int l = 0; l < NBL; ++l) s += d[l] * (float)frac[t * NBL + l];
        compat[t * PLANE + xy] = s;
    }
}
__global__ void k_gather_simple(const float* __restrict__ pos, const float* __restrict__ nsx,
                                const float* __restrict__ nsy, const int* __restrict__ idx,
                                const int* __restrict__ ltyp, const float* __restrict__ compat,
                                float* __restrict__ out, int n, int Linst) {
    int i = blockIdx.x * blockDim.x + threadIdx.x;
    if (i >= Linst) return;
    int id = idx[i];
    float sx = nsx[id], sy = nsy[id];
    float cx = pos[id] + 0.5f * sx, cy = pos[n + id] + 0.5f * sy;
    float gx[W], gy[W]; int bx[W], by[W];
    axis_frag_fb(cx, NBX, gx, bx);
    axis_frag_fb(cy, NBY, gy, by);
    const float* plane = compat + ltyp[id] * PLANE;
    float sum = 0.0f;
#pragma unroll
    for (int jx = 0; jx < W; ++jx) {
        float wx = gx[jx];
        const float* row = plane + bx[jx] * NBY;
#pragma unroll
        for (int jy = 0; jy < W; ++jy) sum += wx * gy[jy] * row[by[jy]];
    }
    out[id] = sum * INV_CAP;
}

extern "C" void kernel_launch(void* const* d_in, const int* in_sizes, int n_in,
                              void* d_out, int out_size, void* d_ws, size_t ws_size,
                              hipStream_t stream) {
    const float* pos  = (const float*)d_in[0];
    const float* nsx  = (const float*)d_in[1];
    const float* nsy  = (const float*)d_in[2];
    const int*   idx  = (const int*)d_in[3];
    const int*   ltyp = (const int*)d_in[4];
    const int*   frac = (const int*)d_in[5];
    int n     = in_sizes[1];
    int Linst = in_sizes[3];
    float* out = (float*)d_out;
    const int bs = 256;

    size_t SBYTES = (size_t)NT * CAP * 16;                 /* slot array ~27.5 MB */
    size_t need = SBYTES
                + (size_t)NT * SPLITD * SLABP * 4          /* partial slabs ~8.2 MB */
                + (size_t)NT * 4;                          /* tileCount */

    if (ws_size >= need) {
        char* base = (char*)d_ws;
        float4* sorted  = (float4*)base;
        float* slabs    = (float*)(base + SBYTES);
        int* tileCount  = (int*)(slabs + (size_t)NT * SPLITD * SLABP);

        hipMemsetAsync(tileCount, 0, NT * sizeof(int), stream);
        hipMemsetAsync(out, 0, (size_t)out_size * sizeof(float), stream);

        int sortGrid = (Linst + WIN - 1) / WIN;
        k_sort<<<sortGrid, bs, 0, stream>>>(pos, nsx, nsy, idx, ltyp,
                                            tileCount, sorted, n, Linst);
        k_demand3<<<NT * SPLITD, GPT, 0, stream>>>(sorted, tileCount, slabs);
        k_out3<<<NT * SPLITD, bs, 0, stream>>>(sorted, tileCount, slabs, frac, out);
    } else {
        float* dem    = (float*)d_ws;
        float* compat = dem + MAPSZ;
        hipMemsetAsync(dem, 0, MAPSZ * sizeof(float), stream);
        hipMemsetAsync(out, 0, (size_t)out_size * sizeof(float), stream);
        k_demand_atomic<<<(Linst + bs - 1) / bs, bs, 0, stream>>>(pos, nsx, nsy, idx, ltyp, dem, n, Linst);
        k_compat_simple<<<(PLANE + bs - 1) / bs, bs, 0, stream>>>(dem, frac, compat);
        k_gather_simple<<<(Linst + bs - 1) / bs, bs, 0, stream>>>(pos, nsx, nsy, idx, ltyp, compat, out, n, Linst);
    }
}

// Round 13
// 171.648 us; speedup vs baseline: 1.1288x; 1.1288x over previous
//
#include <hip/hip_runtime.h>
#include <math.h>

#define NBX 168
#define NBY 480
#define NBL 6
#define PLANE (NBX * NBY)
#define MAPSZ (PLANE * NBL)
#define EXT 2
#define W 5
#define INV_SQRT2 0.70710678118654752440f
#define INV_CAP 0.0625f

/* ---- spatial tiling: NT = 768 = exactly 3 blocks/CU x 256 CUs -> the
   per-tile kernels execute in ONE occupancy round (R12 two-point fit:
   block latency ~= 12us fixed + ~10us/tile-items; rounds dominate). ---- */
#define TW 7                     /* tile width in x-bins  (168/7  = 24) */
#define TH 15                    /* tile height in y-bins (480/15 = 32) */
#define TX (NBX / TW)            /* 24 */
#define TY (NBY / TH)            /* 32 */
#define NT (TX * TY)             /* 768 tiles */
#define GPT (TW * TH * NBL)      /* 630 (cell,type) groups per tile */
#define BLOCKD 640               /* demand block: 10 waves (630 active groups) */
#define NWAVES (BLOCKD / 64)     /* 10 */
#define LTW (TW + 2 * EXT)       /* 11 */
#define LTH (TH + 2 * EXT)       /* 19 */
#define LTHP 19                  /* 19 odd -> coprime w/ 32 banks, no pad */
#define TSTRIDE (LTW * LTHP)     /* 209 */
#define SLABP (NBL * TSTRIDE)    /* 1254 floats = 5.0 KB */
#define BATCH 704                /* items per LDS batch (1302 mean -> 2 batches) */
#define WSTR 13                  /* weight-record stride: coprime w/ 32 banks */
#define CAP 2048                 /* payload slots per tile (mean 1302, sd ~36) */
#define WIN 2048                 /* items staged per LDS window in k_sort */
#define SORT_BLOCKS 256

/* Branch-free erf, Abramowitz-Stegun 7.1.26 (|err| <= 1.5e-7, |x| <= 2.14 here). */
__device__ __forceinline__ float erf_fast(float x) {
    float ax = fabsf(x);
    float t = __builtin_amdgcn_rcpf(fmaf(0.3275911f, ax, 1.0f));
    float p = fmaf(1.061405429f, t, -1.453152027f);
    p = fmaf(p, t, 1.421413741f);
    p = fmaf(p, t, -0.284496736f);
    p = fmaf(p, t, 0.254829592f);
    p = p * t;
    float e = __expf(-ax * ax);
    float r = fmaf(-p, e, 1.0f);
    return copysignf(r, x);
}

/* 5 axis weights (zeroed for out-of-range bins). */
__device__ __forceinline__ void axis_w(float c, int nb, float* g) {
    int b0 = (int)floorf(c);
    float t0 = (float)(b0 - EXT) - c;
    float e[W + 1];
#pragma unroll
    for (int k = 0; k <= W; ++k) e[k] = erf_fast((t0 + (float)k) * INV_SQRT2);
#pragma unroll
    for (int j = 0; j < W; ++j) {
        int b = b0 - EXT + j;
        g[j] = (b >= 0 && b < nb) ? 0.5f * (e[j + 1] - e[j]) : 0.0f;
    }
}

__device__ __forceinline__ int tile_of_xy(float cx, float cy) {
    int bx = (int)floorf(cx); bx = bx < 0 ? 0 : (bx > NBX - 1 ? NBX - 1 : bx);
    int by = (int)floorf(cy); by = by < 0 ? 0 : (by > NBY - 1 ? NBY - 1 : by);
    return (bx / TW) * TY + (by / TH);
}

__device__ __forceinline__ int group_key(float4 p, int x0, int y0) {
    int bx = (int)floorf(p.x) - x0;
    int by = (int)floorf(p.y) - y0;
    bx = bx < 0 ? 0 : (bx > TW - 1 ? TW - 1 : bx);
    by = by < 0 ? 0 : (by > TH - 1 ? TH - 1 : by);
    return (bx * TH + by) * NBL + (__float_as_int(p.w) & 7);
}

/* Pass 1 (fused build+hist+scan+scatter): windowed LDS staging; one global
   reservation atomic per (block,window,tile); payloads land in fixed
   CAP-sized per-tile slots. R10 shape (256 blocks, WIN 2048). */
__global__ void k_sort(const float* __restrict__ pos, const float* __restrict__ nsx,
                       const float* __restrict__ nsy, const int* __restrict__ idx,
                       const int* __restrict__ ltyp,
                       int* __restrict__ tileCount, float4* __restrict__ sorted,
                       int n, int Linst) {
    __shared__ float4 buf[WIN];
    __shared__ int cnt[NT];
    __shared__ int base[NT];
    int chunk = (Linst + gridDim.x - 1) / gridDim.x;
    int lo = blockIdx.x * chunk;
    int hi = lo + chunk; if (hi > Linst) hi = Linst;
    for (int w0 = lo; w0 < hi; w0 += WIN) {
        int wn = hi - w0; if (wn > WIN) wn = WIN;
        for (int t = threadIdx.x; t < NT; t += blockDim.x) cnt[t] = 0;
        __syncthreads();
        for (int j = threadIdx.x; j < wn; j += blockDim.x) {
            int i = w0 + j;
            int id = idx[i];
            float sx = nsx[id], sy = nsy[id];
            float cx = pos[id] + 0.5f * sx;
            float cy = pos[n + id] + 0.5f * sy;
            buf[j] = make_float4(cx, cy, sx * sy,
                                 __int_as_float((id << 3) | (ltyp[id] & 7)));
            atomicAdd(&cnt[tile_of_xy(cx, cy)], 1);
        }
        __syncthreads();
        for (int t = threadIdx.x; t < NT; t += blockDim.x) {
            base[t] = cnt[t] ? atomicAdd(&tileCount[t], cnt[t]) : 0;
            cnt[t] = 0;                 /* reuse as local cursor */
        }
        __syncthreads();
        for (int j = threadIdx.x; j < wn; j += blockDim.x) {
            float4 p = buf[j];
            int t = tile_of_xy(p.x, p.y);
            int r = base[t] + atomicAdd(&cnt[t], 1);
            if (r < CAP) sorted[(size_t)t * CAP + r] = p;   /* overflow guard */
        }
        __syncthreads();
    }
}

/* Pass 2 (fused subsort+demand): 768 blocks of 640 thr (10 waves), 3/CU ->
   single occupancy round. Threads 630..639 are ghosts: group-less (v=0),
   their merge addresses (lx=7) are disjoint from all real cells (lx<=6),
   and they add 0.0 — provably race-free and value-safe. */
__global__ __launch_bounds__(BLOCKD) void k_demand3(const float4* __restrict__ sorted,
                                                    const int* __restrict__ tileCount,
                                                    float* __restrict__ slabs) {
    __shared__ float wbuf[BATCH * WSTR];
    __shared__ unsigned short keys[BATCH];
    __shared__ unsigned short order[BATCH];
    __shared__ int h[BLOCKD];
    __shared__ int cur[BLOCKD];
    __shared__ int wsum[NWAVES];
    __shared__ float slab[SLABP];
    int t = blockIdx.x, tid = threadIdx.x;
    int cntT = tileCount[t]; if (cntT > CAP) cntT = CAP;
    const float4* src = sorted + (size_t)t * CAP;
    int x0 = (t / TY) * TW, y0 = (t % TY) * TH;
    for (int s = tid; s < SLABP; s += BLOCKD) slab[s] = 0.0f;
    int typ = tid % NBL, lc = tid / NBL;
    int lx = lc / TH, ly = lc % TH;      /* ghosts: lx == 7 (disjoint) */
    int lane = tid & 63, wv = tid >> 6;
    float acc[W * W];
#pragma unroll
    for (int k = 0; k < W * W; ++k) acc[k] = 0.0f;

    for (int b = 0; b < cntT; b += BATCH) {
        int cnt = cntT - b; if (cnt > BATCH) cnt = BATCH;
        h[tid] = 0;
        __syncthreads();
        /* phase 1: balanced erf + weight store + hist */
        for (int j = tid; j < cnt; j += BLOCKD) {
            float4 p = src[b + j];
            int key = group_key(p, x0, y0);
            keys[j] = (unsigned short)key;
            float gx[W], gy[W];
            axis_w(p.x, NBX, gx);
            axis_w(p.y, NBY, gy);
            float* wr = &wbuf[j * WSTR];
#pragma unroll
            for (int k = 0; k < W; ++k) wr[k] = gx[k] * p.z;
#pragma unroll
            for (int k = 0; k < W; ++k) wr[W + k] = gy[k];
            atomicAdd(&h[key], 1);
        }
        __syncthreads();
        int v = h[tid];                     /* ghosts: 0 */
        int sc = v;                         /* wave-level inclusive scan */
#pragma unroll
        for (int off = 1; off < 64; off <<= 1) {
            int u = __shfl_up(sc, off);
            if (lane >= off) sc += u;
        }
        if (lane == 63) wsum[wv] = sc;
        __syncthreads();
        int wbase = 0;
        for (int w2 = 0; w2 < wv; ++w2) wbase += wsum[w2];
        int myStart = wbase + sc - v;
        cur[tid] = myStart;
        __syncthreads();
        for (int j = tid; j < cnt; j += BLOCKD) {
            int r = atomicAdd(&cur[(int)keys[j]], 1);
            order[r] = (unsigned short)j;
        }
        __syncthreads();
        /* phase 2: group-gather (divergent but cheap) */
        for (int k = 0; k < v; ++k) {
            const float* wr = &wbuf[(int)order[myStart + k] * WSTR];
            float gxp[W], gy[W];
#pragma unroll
            for (int q = 0; q < W; ++q) gxp[q] = wr[q];
#pragma unroll
            for (int q = 0; q < W; ++q) gy[q] = wr[W + q];
#pragma unroll
            for (int jx = 0; jx < W; ++jx) {
#pragma unroll
                for (int jy = 0; jy < W; ++jy)
                    acc[jx * W + jy] = fmaf(gxp[jx], gy[jy], acc[jx * W + jy]);
            }
        }
        __syncthreads();                    /* wbuf/h reuse fence */
    }

    int bse = typ * TSTRIDE + lx * LTHP + ly;
#pragma unroll
    for (int jx = 0; jx < W; ++jx) {
#pragma unroll
        for (int jy = 0; jy < W; ++jy) {
            __syncthreads();
            slab[bse + jx * LTHP + jy] += acc[jx * W + jy];   /* 0-add ok */
        }
    }
    __syncthreads();
    float* o = slabs + (size_t)t * SLABP;
    for (int s = tid; s < SLABP; s += BLOCKD) o[s] = slab[s];
}

/* Pass 3 (fused compat+gather): per tile — assemble the tile's compat
   region in LDS from neighbor slabs + 6x6 fracture einsum, then one
   thread per INSTANCE: 12 dense erfs, 25 LDS reads, dot, store. */
__global__ void k_out3(const float4* __restrict__ sorted,
                       const int* __restrict__ tileCount,
                       const float* __restrict__ slabs,
                       const int* __restrict__ frac,
                       float* __restrict__ out) {
    __shared__ float cc[SLABP];
    __shared__ float fr[NBL * NBL];
    int t = blockIdx.x;
    int x0 = (t / TY) * TW, y0 = (t % TY) * TH;
    if (threadIdx.x < NBL * NBL) fr[threadIdx.x] = (float)frac[threadIdx.x];
    __syncthreads();
    for (int s = threadIdx.x; s < LTW * LTH; s += blockDim.x) {
        int lxx = s / LTH, lyy = s % LTH;
        int x = x0 - EXT + lxx, y = y0 - EXT + lyy;
        float d[NBL] = {0, 0, 0, 0, 0, 0};
        if (x >= 0 && x < NBX && y >= 0 && y < NBY) {
            int tx = x / TW, xm = x % TW;
            int ty = y / TH, ym = y % TH;
            int ax0 = (xm < EXT && tx > 0) ? tx - 1 : tx;
            int ax1 = (xm >= TW - EXT && tx < TX - 1) ? tx + 1 : tx;
            int ay0 = (ym < EXT && ty > 0) ? ty - 1 : ty;
            int ay1 = (ym >= TH - EXT && ty < TY - 1) ? ty + 1 : ty;
            for (int ax = ax0; ax <= ax1; ++ax)
                for (int ay = ay0; ay <= ay1; ++ay) {
                    int lx = x - (ax * TW - EXT);
                    int ly = y - (ay * TH - EXT);
                    const float* sl = slabs + (size_t)(ax * TY + ay) * SLABP
                                      + lx * LTHP + ly;
#pragma unroll
                    for (int l = 0; l < NBL; ++l) d[l] += sl[l * TSTRIDE];
                }
        }
#pragma unroll
        for (int tt = 0; tt < NBL; ++tt) {
            float s2 = 0.0f;
#pragma unroll
            for (int l = 0; l < NBL; ++l) s2 += d[l] * fr[tt * NBL + l];
            cc[tt * TSTRIDE + lxx * LTHP + lyy] = s2;
        }
    }
    __syncthreads();
    int cntT = tileCount[t]; if (cntT > CAP) cntT = CAP;
    const float4* src = sorted + (size_t)t * CAP;
    for (int j = threadIdx.x; j < cntT; j += blockDim.x) {
        float4 p = src[j];
        int packed = __float_as_int(p.w);
        int typ = packed & 7;
        float gxw[W], gyw[W];
        axis_w(p.x, NBX, gxw);
        axis_w(p.y, NBY, gyw);
        int lx = (int)floorf(p.x) - x0, ly = (int)floorf(p.y) - y0;
        lx = lx < 0 ? 0 : (lx > TW - 1 ? TW - 1 : lx);
        ly = ly < 0 ? 0 : (ly > TH - 1 ? TH - 1 : ly);
        int base = typ * TSTRIDE + lx * LTHP + ly;
        float sum = 0.0f;
#pragma unroll
        for (int jx = 0; jx < W; ++jx) {
            float row = 0.0f;
#pragma unroll
            for (int jy = 0; jy < W; ++jy)
                row = fmaf(gyw[jy], cc[base + jx * LTHP + jy], row);
            sum = fmaf(gxw[jx], row, sum);
        }
        out[packed >> 3] = sum * INV_CAP;
    }
}

/* ---------- fallback (atomic path) if ws_size is too small ---------- */
__device__ __forceinline__ void axis_frag_fb(float c, int nb, float* g, int* bc) {
    int b0 = (int)floorf(c);
    float t0 = (float)(b0 - EXT) - c;
    float e[W + 1];
#pragma unroll
    for (int k = 0; k <= W; ++k) e[k] = erf_fast((t0 + (float)k) * INV_SQRT2);
#pragma unroll
    for (int j = 0; j < W; ++j) {
        int b = b0 - EXT + j;
        g[j] = (b >= 0 && b < nb) ? 0.5f * (e[j + 1] - e[j]) : 0.0f;
        int bcl = b < 0 ? 0 : b;
        bc[j] = bcl > nb - 1 ? nb - 1 : bcl;
    }
}
__global__ void k_demand_atomic(const float* __restrict__ pos, const float* __restrict__ nsx,
                                const float* __restrict__ nsy, const int* __restrict__ idx,
                                const int* __restrict__ ltyp, float* __restrict__ dem,
                                int n, int Linst) {
    int i = blockIdx.x * blockDim.x + threadIdx.x;
    if (i >= Linst) return;
    int id = idx[i];
    float sx = nsx[id], sy = nsy[id];
    float cx = pos[id] + 0.5f * sx, cy = pos[n + id] + 0.5f * sy;
    float area = sx * sy;
    float gx[W], gy[W]; int bx[W], by[W];
    axis_frag_fb(cx, NBX, gx, bx);
    axis_frag_fb(cy, NBY, gy, by);
    float* plane = dem + ltyp[id] * PLANE;
#pragma unroll
    for (int jx = 0; jx < W; ++jx) {
        float wx = gx[jx] * area;
        if (wx == 0.0f) continue;
        float* row = plane + bx[jx] * NBY;
#pragma unroll
        for (int jy = 0; jy < W; ++jy) {
            float w = wx * gy[jy];
            if (w != 0.0f) atomicAdd(row + by[jy], w);
        }
    }
}
__global__ void k_compat_simple(const float* __restrict__ dem, const int* __restrict__ frac,
                                float* __restrict__ compat) {
    int xy = blockIdx.x * blockDim.x + threadIdx.x;
    if (xy >= PLANE) return;
    float d[NBL];
#pragma unroll
    for (int l = 0; l < NBL; ++l) d[l] = dem[l * PLANE + xy];
#pragma unroll
    for (int t = 0; t < NBL; ++t) {
        float s = 0.0f;
#pragma unroll
        for (int l = 0; l < NBL; ++l) s += d[l] * (float)frac[t * NBL + l];
        compat[t * PLANE + xy] = s;
    }
}
__global__ void k_gather_simple(const float* __restrict__ pos, const float* __restrict__ nsx,
                                const float* __restrict__ nsy, const int* __restrict__ idx,
                                const int* __restrict__ ltyp, const float* __restrict__ compat,
                                float* __restrict__ out, int n, int Linst) {
    int i = blockIdx.x * blockDim.x + threadIdx.x;
    if (i >= Linst) return;
    int id = idx[i];
    float sx = nsx[id], sy = nsy[id];
    float cx = pos[id] + 0.5f * sx, cy = pos[n + id] + 0.5f * sy;
    float gx[W], gy[W]; int bx[W], by[W];
    axis_frag_fb(cx, NBX, gx, bx);
    axis_frag_fb(cy, NBY, gy, by);
    const float* plane = compat + ltyp[id] * PLANE;
    float sum = 0.0f;
#pragma unroll
    for (int jx = 0; jx < W; ++jx) {
        float wx = gx[jx];
        const float* row = plane + bx[jx] * NBY;
#pragma unroll
        for (int jy = 0; jy < W; ++jy) sum += wx * gy[jy] * row[by[jy]];
    }
    out[id] = sum * INV_CAP;
}

extern "C" void kernel_launch(void* const* d_in, const int* in_sizes, int n_in,
                              void* d_out, int out_size, void* d_ws, size_t ws_size,
                              hipStream_t stream) {
    const float* pos  = (const float*)d_in[0];
    const float* nsx  = (const float*)d_in[1];
    const float* nsy  = (const float*)d_in[2];
    const int*   idx  = (const int*)d_in[3];
    const int*   ltyp = (const int*)d_in[4];
    const int*   frac = (const int*)d_in[5];
    int n     = in_sizes[1];
    int Linst = in_sizes[3];
    float* out = (float*)d_out;
    const int bs = 256;

    size_t SBYTES = (size_t)NT * CAP * 16;                 /* slot array ~25 MB */
    size_t need = SBYTES
                + (size_t)NT * SLABP * 4                   /* slabs ~3.9 MB */
                + (size_t)NT * 4;                          /* tileCount */

    if (ws_size >= need) {
        char* base = (char*)d_ws;
        float4* sorted  = (float4*)base;
        float* slabs    = (float*)(base + SBYTES);
        int* tileCount  = (int*)(slabs + (size_t)NT * SLABP);

        hipMemsetAsync(tileCount, 0, NT * sizeof(int), stream);
        hipMemsetAsync(out, 0, (size_t)out_size * sizeof(float), stream);

        k_sort<<<SORT_BLOCKS, bs, 0, stream>>>(pos, nsx, nsy, idx, ltyp,
                                               tileCount, sorted, n, Linst);
        k_demand3<<<NT, BLOCKD, 0, stream>>>(sorted, tileCount, slabs);
        k_out3<<<NT, bs, 0, stream>>>(sorted, tileCount, slabs, frac, out);
    } else {
        float* dem    = (float*)d_ws;
        float* compat = dem + MAPSZ;
        hipMemsetAsync(dem, 0, MAPSZ * sizeof(float), stream);
        hipMemsetAsync(out, 0, (size_t)out_size * sizeof(float), stream);
        k_demand_atomic<<<(Linst + bs - 1) / bs, bs, 0, stream>>>(pos, nsx, nsy, idx, ltyp, dem, n, Linst);
        k_compat_simple<<<(PLANE + bs - 1) / bs, bs, 0, stream>>>(dem, frac, compat);
        k_gather_simple<<<(Linst + bs - 1) / bs, bs, 0, stream>>>(pos, nsx, nsy, idx, ltyp, compat, out, n, Linst);
    }
}

// Round 14
// 160.960 us; speedup vs baseline: 1.2037x; 1.0664x over previous
//
#include <hip/hip_runtime.h>
#include <math.h>

#define NBX 168
#define NBY 480
#define NBL 6
#define PLANE (NBX * NBY)
#define MAPSZ (PLANE * NBL)
#define EXT 2
#define W 5
#define INV_SQRT2 0.70710678118654752440f
#define INV_CAP 0.0625f

/* ---- spatial tiling: NT = 768 = 3 blocks/CU x 256 CUs -> per-tile
   kernels run in ONE occupancy round (confirmed R13: -22us). ---- */
#define TW 7                     /* tile width in x-bins  (168/7  = 24) */
#define TH 15                    /* tile height in y-bins (480/15 = 32) */
#define TX (NBX / TW)            /* 24 */
#define TY (NBY / TH)            /* 32 */
#define NT (TX * TY)             /* 768 tiles */
#define GPT (TW * TH * NBL)      /* 630 (cell,type) groups per tile */
#define BLOCKD 640               /* demand block: 10 waves (630 active groups) */
#define NWAVES (BLOCKD / 64)     /* 10 */
#define LTW (TW + 2 * EXT)       /* 11 */
#define LTH (TH + 2 * EXT)       /* 19 */
#define LTHP 19                  /* odd -> coprime w/ 32 banks, no pad */
#define TSTRIDE (LTW * LTHP)     /* 209 */
#define SLABP (NBL * TSTRIDE)    /* 1254 floats = 5.0 KB */
#define BATCH 704                /* items per LDS batch (1302 mean -> 2 batches) */
#define WSTR 13                  /* weight-record stride: coprime w/ 32 banks */
#define CAP 2048                 /* payload slots per tile (mean 1302, sd ~36) */
#define WIN 4096                 /* items per k_sort window: halves reservation
                                    atomics (R1 law: ~19.6G dev-atomics/s ->
                                    350K was ~18us of atomic pipe) */
#define SORT_BS 512              /* 8 waves/CU (was 4) for gather hiding */
#define OUT_BS 512               /* 24 waves/CU for k_out3 */

/* Branch-free erf, Abramowitz-Stegun 7.1.26 (|err| <= 1.5e-7, |x| <= 2.14 here). */
__device__ __forceinline__ float erf_fast(float x) {
    float ax = fabsf(x);
    float t = __builtin_amdgcn_rcpf(fmaf(0.3275911f, ax, 1.0f));
    float p = fmaf(1.061405429f, t, -1.453152027f);
    p = fmaf(p, t, 1.421413741f);
    p = fmaf(p, t, -0.284496736f);
    p = fmaf(p, t, 0.254829592f);
    p = p * t;
    float e = __expf(-ax * ax);
    float r = fmaf(-p, e, 1.0f);
    return copysignf(r, x);
}

/* 5 axis weights (zeroed for out-of-range bins). */
__device__ __forceinline__ void axis_w(float c, int nb, float* g) {
    int b0 = (int)floorf(c);
    float t0 = (float)(b0 - EXT) - c;
    float e[W + 1];
#pragma unroll
    for (int k = 0; k <= W; ++k) e[k] = erf_fast((t0 + (float)k) * INV_SQRT2);
#pragma unroll
    for (int j = 0; j < W; ++j) {
        int b = b0 - EXT + j;
        g[j] = (b >= 0 && b < nb) ? 0.5f * (e[j + 1] - e[j]) : 0.0f;
    }
}

__device__ __forceinline__ int tile_of_xy(float cx, float cy) {
    int bx = (int)floorf(cx); bx = bx < 0 ? 0 : (bx > NBX - 1 ? NBX - 1 : bx);
    int by = (int)floorf(cy); by = by < 0 ? 0 : (by > NBY - 1 ? NBY - 1 : by);
    return (bx / TW) * TY + (by / TH);
}

__device__ __forceinline__ int group_key(float4 p, int x0, int y0) {
    int bx = (int)floorf(p.x) - x0;
    int by = (int)floorf(p.y) - y0;
    bx = bx < 0 ? 0 : (bx > TW - 1 ? TW - 1 : bx);
    by = by < 0 ? 0 : (by > TH - 1 ? TH - 1 : by);
    return (bx * TH + by) * NBL + (__float_as_int(p.w) & 7);
}

/* Pass 1 (fused build+hist+scan+scatter): one 4096-item LDS window per
   block; one global reservation atomic per (window,tile). */
__global__ __launch_bounds__(SORT_BS) void k_sort(
        const float* __restrict__ pos, const float* __restrict__ nsx,
        const float* __restrict__ nsy, const int* __restrict__ idx,
        const int* __restrict__ ltyp,
        int* __restrict__ tileCount, float4* __restrict__ sorted,
        int n, int Linst) {
    __shared__ float4 buf[WIN];
    __shared__ int cnt[NT];
    __shared__ int base[NT];
    int chunk = (Linst + gridDim.x - 1) / gridDim.x;
    int lo = blockIdx.x * chunk;
    int hi = lo + chunk; if (hi > Linst) hi = Linst;
    for (int w0 = lo; w0 < hi; w0 += WIN) {
        int wn = hi - w0; if (wn > WIN) wn = WIN;
        for (int t = threadIdx.x; t < NT; t += blockDim.x) cnt[t] = 0;
        __syncthreads();
        for (int j = threadIdx.x; j < wn; j += blockDim.x) {
            int i = w0 + j;
            int id = idx[i];
            float sx = nsx[id], sy = nsy[id];
            float cx = pos[id] + 0.5f * sx;
            float cy = pos[n + id] + 0.5f * sy;
            buf[j] = make_float4(cx, cy, sx * sy,
                                 __int_as_float((id << 3) | (ltyp[id] & 7)));
            atomicAdd(&cnt[tile_of_xy(cx, cy)], 1);
        }
        __syncthreads();
        for (int t = threadIdx.x; t < NT; t += blockDim.x) {
            base[t] = cnt[t] ? atomicAdd(&tileCount[t], cnt[t]) : 0;
            cnt[t] = 0;                 /* reuse as local cursor */
        }
        __syncthreads();
        for (int j = threadIdx.x; j < wn; j += blockDim.x) {
            float4 p = buf[j];
            int t = tile_of_xy(p.x, p.y);
            int r = base[t] + atomicAdd(&cnt[t], 1);
            if (r < CAP) sorted[(size_t)t * CAP + r] = p;   /* overflow guard */
        }
        __syncthreads();
    }
}

/* Pass 2 (fused subsort+demand): 768 blocks of 640 thr (10 waves), 3/CU ->
   single occupancy round. Ghost threads 630..639: v=0, merge addresses
   disjoint (lx=7 > any real cell), add 0.0 — race-free and value-safe. */
__global__ __launch_bounds__(BLOCKD) void k_demand3(const float4* __restrict__ sorted,
                                                    const int* __restrict__ tileCount,
                                                    float* __restrict__ slabs) {
    __shared__ float wbuf[BATCH * WSTR];
    __shared__ unsigned short keys[BATCH];
    __shared__ unsigned short order[BATCH];
    __shared__ int h[BLOCKD];
    __shared__ int cur[BLOCKD];
    __shared__ int wsum[NWAVES];
    __shared__ float slab[SLABP];
    int t = blockIdx.x, tid = threadIdx.x;
    int cntT = tileCount[t]; if (cntT > CAP) cntT = CAP;
    const float4* src = sorted + (size_t)t * CAP;
    int x0 = (t / TY) * TW, y0 = (t % TY) * TH;
    for (int s = tid; s < SLABP; s += BLOCKD) slab[s] = 0.0f;
    int typ = tid % NBL, lc = tid / NBL;
    int lx = lc / TH, ly = lc % TH;      /* ghosts: lx == 7 (disjoint) */
    int lane = tid & 63, wv = tid >> 6;
    float acc[W * W];
#pragma unroll
    for (int k = 0; k < W * W; ++k) acc[k] = 0.0f;

    for (int b = 0; b < cntT; b += BATCH) {
        int cnt = cntT - b; if (cnt > BATCH) cnt = BATCH;
        h[tid] = 0;
        __syncthreads();
        /* phase 1: balanced erf + weight store + hist */
        for (int j = tid; j < cnt; j += BLOCKD) {
            float4 p = src[b + j];
            int key = group_key(p, x0, y0);
            keys[j] = (unsigned short)key;
            float gx[W], gy[W];
            axis_w(p.x, NBX, gx);
            axis_w(p.y, NBY, gy);
            float* wr = &wbuf[j * WSTR];
#pragma unroll
            for (int k = 0; k < W; ++k) wr[k] = gx[k] * p.z;
#pragma unroll
            for (int k = 0; k < W; ++k) wr[W + k] = gy[k];
            atomicAdd(&h[key], 1);
        }
        __syncthreads();
        int v = h[tid];                     /* ghosts: 0 */
        int sc = v;                         /* wave-level inclusive scan */
#pragma unroll
        for (int off = 1; off < 64; off <<= 1) {
            int u = __shfl_up(sc, off);
            if (lane >= off) sc += u;
        }
        if (lane == 63) wsum[wv] = sc;
        __syncthreads();
        int wbase = 0;
        for (int w2 = 0; w2 < wv; ++w2) wbase += wsum[w2];
        int myStart = wbase + sc - v;
        cur[tid] = myStart;
        __syncthreads();
        for (int j = tid; j < cnt; j += BLOCKD) {
            int r = atomicAdd(&cur[(int)keys[j]], 1);
            order[r] = (unsigned short)j;
        }
        __syncthreads();
        /* phase 2: group-gather (divergent but cheap) */
        for (int k = 0; k < v; ++k) {
            const float* wr = &wbuf[(int)order[myStart + k] * WSTR];
            float gxp[W], gy[W];
#pragma unroll
            for (int q = 0; q < W; ++q) gxp[q] = wr[q];
#pragma unroll
            for (int q = 0; q < W; ++q) gy[q] = wr[W + q];
#pragma unroll
            for (int jx = 0; jx < W; ++jx) {
#pragma unroll
                for (int jy = 0; jy < W; ++jy)
                    acc[jx * W + jy] = fmaf(gxp[jx], gy[jy], acc[jx * W + jy]);
            }
        }
        __syncthreads();                    /* wbuf/h reuse fence */
    }

    int bse = typ * TSTRIDE + lx * LTHP + ly;
#pragma unroll
    for (int jx = 0; jx < W; ++jx) {
#pragma unroll
        for (int jy = 0; jy < W; ++jy) {
            __syncthreads();
            slab[bse + jx * LTHP + jy] += acc[jx * W + jy];   /* 0-add ok */
        }
    }
    __syncthreads();
    float* o = slabs + (size_t)t * SLABP;
    for (int s = tid; s < SLABP; s += BLOCKD) o[s] = slab[s];
}

/* Pass 3 (fused compat+gather): 512-thr blocks (24 waves/CU) — assemble
   the tile's compat region in LDS from neighbor slabs + 6x6 fracture
   einsum, then one thread per INSTANCE: 12 erfs, 25 LDS reads, dot, store. */
__global__ __launch_bounds__(OUT_BS) void k_out3(const float4* __restrict__ sorted,
                                                 const int* __restrict__ tileCount,
                                                 const float* __restrict__ slabs,
                                                 const int* __restrict__ frac,
                                                 float* __restrict__ out) {
    __shared__ float cc[SLABP];
    __shared__ float fr[NBL * NBL];
    int t = blockIdx.x;
    int x0 = (t / TY) * TW, y0 = (t % TY) * TH;
    if (threadIdx.x < NBL * NBL) fr[threadIdx.x] = (float)frac[threadIdx.x];
    __syncthreads();
    for (int s = threadIdx.x; s < LTW * LTH; s += blockDim.x) {
        int lxx = s / LTH, lyy = s % LTH;
        int x = x0 - EXT + lxx, y = y0 - EXT + lyy;
        float d[NBL] = {0, 0, 0, 0, 0, 0};
        if (x >= 0 && x < NBX && y >= 0 && y < NBY) {
            int tx = x / TW, xm = x % TW;
            int ty = y / TH, ym = y % TH;
            int ax0 = (xm < EXT && tx > 0) ? tx - 1 : tx;
            int ax1 = (xm >= TW - EXT && tx < TX - 1) ? tx + 1 : tx;
            int ay0 = (ym < EXT && ty > 0) ? ty - 1 : ty;
            int ay1 = (ym >= TH - EXT && ty < TY - 1) ? ty + 1 : ty;
            for (int ax = ax0; ax <= ax1; ++ax)
                for (int ay = ay0; ay <= ay1; ++ay) {
                    int lx = x - (ax * TW - EXT);
                    int ly = y - (ay * TH - EXT);
                    const float* sl = slabs + (size_t)(ax * TY + ay) * SLABP
                                      + lx * LTHP + ly;
#pragma unroll
                    for (int l = 0; l < NBL; ++l) d[l] += sl[l * TSTRIDE];
                }
        }
#pragma unroll
        for (int tt = 0; tt < NBL; ++tt) {
            float s2 = 0.0f;
#pragma unroll
            for (int l = 0; l < NBL; ++l) s2 += d[l] * fr[tt * NBL + l];
            cc[tt * TSTRIDE + lxx * LTHP + lyy] = s2;
        }
    }
    __syncthreads();
    int cntT = tileCount[t]; if (cntT > CAP) cntT = CAP;
    const float4* src = sorted + (size_t)t * CAP;
    for (int j = threadIdx.x; j < cntT; j += blockDim.x) {
        float4 p = src[j];
        int packed = __float_as_int(p.w);
        int typ = packed & 7;
        float gxw[W], gyw[W];
        axis_w(p.x, NBX, gxw);
        axis_w(p.y, NBY, gyw);
        int lx = (int)floorf(p.x) - x0, ly = (int)floorf(p.y) - y0;
        lx = lx < 0 ? 0 : (lx > TW - 1 ? TW - 1 : lx);
        ly = ly < 0 ? 0 : (ly > TH - 1 ? TH - 1 : ly);
        int base = typ * TSTRIDE + lx * LTHP + ly;
        float sum = 0.0f;
#pragma unroll
        for (int jx = 0; jx < W; ++jx) {
            float row = 0.0f;
#pragma unroll
            for (int jy = 0; jy < W; ++jy)
                row = fmaf(gyw[jy], cc[base + jx * LTHP + jy], row);
            sum = fmaf(gxw[jx], row, sum);
        }
        out[packed >> 3] = sum * INV_CAP;
    }
}

/* ---------- fallback (atomic path) if ws_size is too small ---------- */
__device__ __forceinline__ void axis_frag_fb(float c, int nb, float* g, int* bc) {
    int b0 = (int)floorf(c);
    float t0 = (float)(b0 - EXT) - c;
    float e[W + 1];
#pragma unroll
    for (int k = 0; k <= W; ++k) e[k] = erf_fast((t0 + (float)k) * INV_SQRT2);
#pragma unroll
    for (int j = 0; j < W; ++j) {
        int b = b0 - EXT + j;
        g[j] = (b >= 0 && b < nb) ? 0.5f * (e[j + 1] - e[j]) : 0.0f;
        int bcl = b < 0 ? 0 : b;
        bc[j] = bcl > nb - 1 ? nb - 1 : bcl;
    }
}
__global__ void k_demand_atomic(const float* __restrict__ pos, const float* __restrict__ nsx,
                                const float* __restrict__ nsy, const int* __restrict__ idx,
                                const int* __restrict__ ltyp, float* __restrict__ dem,
                                int n, int Linst) {
    int i = blockIdx.x * blockDim.x + threadIdx.x;
    if (i >= Linst) return;
    int id = idx[i];
    float sx = nsx[id], sy = nsy[id];
    float cx = pos[id] + 0.5f * sx, cy = pos[n + id] + 0.5f * sy;
    float area = sx * sy;
    float gx[W], gy[W]; int bx[W], by[W];
    axis_frag_fb(cx, NBX, gx, bx);
    axis_frag_fb(cy, NBY, gy, by);
    float* plane = dem + ltyp[id] * PLANE;
#pragma unroll
    for (int jx = 0; jx < W; ++jx) {
        float wx = gx[jx] * area;
        if (wx == 0.0f) continue;
        float* row = plane + bx[jx] * NBY;
#pragma unroll
        for (int jy = 0; jy < W; ++jy) {
            float w = wx * gy[jy];
            if (w != 0.0f) atomicAdd(row + by[jy], w);
        }
    }
}
__global__ void k_compat_simple(const float* __restrict__ dem, const int* __restrict__ frac,
                                float* __restrict__ compat) {
    int xy = blockIdx.x * blockDim.x + threadIdx.x;
    if (xy >= PLANE) return;
    float d[NBL];
#pragma unroll
    for (int l = 0; l < NBL; ++l) d[l] = dem[l * PLANE + xy];
#pragma unroll
    for (int t = 0; t < NBL; ++t) {
        float s = 0.0f;
#pragma unroll
        for (int l = 0; l < NBL; ++l) s += d[l] * (float)frac[t * NBL + l];
        compat[t * PLANE + xy] = s;
    }
}
__global__ void k_gather_simple(const float* __restrict__ pos, const float* __restrict__ nsx,
                                const float* __restrict__ nsy, const int* __restrict__ idx,
                                const int* __restrict__ ltyp, const float* __restrict__ compat,
                                float* __restrict__ out, int n, int Linst) {
    int i = blockIdx.x * blockDim.x + threadIdx.x;
    if (i >= Linst) return;
    int id = idx[i];
    float sx = nsx[id], sy = nsy[id];
    float cx = pos[id] + 0.5f * sx, cy = pos[n + id] + 0.5f * sy;
    float gx[W], gy[W]; int bx[W], by[W];
    axis_frag_fb(cx, NBX, gx, bx);
    axis_frag_fb(cy, NBY, gy, by);
    const float* plane = compat + ltyp[id] * PLANE;
    float sum = 0.0f;
#pragma unroll
    for (int jx = 0; jx < W; ++jx) {
        float wx = gx[jx];
        const float* row = plane + bx[jx] * NBY;
#pragma unroll
        for (int jy = 0; jy < W; ++jy) sum += wx * gy[jy] * row[by[jy]];
    }
    out[id] = sum * INV_CAP;
}

extern "C" void kernel_launch(void* const* d_in, const int* in_sizes, int n_in,
                              void* d_out, int out_size, void* d_ws, size_t ws_size,
                              hipStream_t stream) {
    const float* pos  = (const float*)d_in[0];
    const float* nsx  = (const float*)d_in[1];
    const float* nsy  = (const float*)d_in[2];
    const int*   idx  = (const int*)d_in[3];
    const int*   ltyp = (const int*)d_in[4];
    const int*   frac = (const int*)d_in[5];
    int n     = in_sizes[1];
    int Linst = in_sizes[3];
    float* out = (float*)d_out;
    const int bs = 256;

    size_t SBYTES = (size_t)NT * CAP * 16;                 /* slot array ~25 MB */
    size_t need = SBYTES
                + (size_t)NT * SLABP * 4                   /* slabs ~3.9 MB */
                + (size_t)NT * 4;                          /* tileCount */

    if (ws_size >= need) {
        char* base = (char*)d_ws;
        float4* sorted  = (float4*)base;
        float* slabs    = (float*)(base + SBYTES);
        int* tileCount  = (int*)(slabs + (size_t)NT * SLABP);

        hipMemsetAsync(tileCount, 0, NT * sizeof(int), stream);
        hipMemsetAsync(out, 0, (size_t)out_size * sizeof(float), stream);

        int sortGrid = (Linst + WIN - 1) / WIN;            /* ~245: one window each */
        k_sort<<<sortGrid, SORT_BS, 0, stream>>>(pos, nsx, nsy, idx, ltyp,
                                                 tileCount, sorted, n, Linst);
        k_demand3<<<NT, BLOCKD, 0, stream>>>(sorted, tileCount, slabs);
        k_out3<<<NT, OUT_BS, 0, stream>>>(sorted, tileCount, slabs, frac, out);
    } else {
        float* dem    = (float*)d_ws;
        float* compat = dem + MAPSZ;
        hipMemsetAsync(dem, 0, MAPSZ * sizeof(float), stream);
        hipMemsetAsync(out, 0, (size_t)out_size * sizeof(float), stream);
        k_demand_atomic<<<(Linst + bs - 1) / bs, bs, 0, stream>>>(pos, nsx, nsy, idx, ltyp, dem, n, Linst);
        k_compat_simple<<<(PLANE + bs - 1) / bs, bs, 0, stream>>>(dem, frac, compat);
        k_gather_simple<<<(Linst + bs - 1) / bs, bs, 0, stream>>>(pos, nsx, nsy, idx, ltyp, compat, out, n, Linst);
    }
}

// Round 15
// 155.611 us; speedup vs baseline: 1.2451x; 1.0344x over previous
//
#include <hip/hip_runtime.h>
#include <math.h>

#define NBX 168
#define NBY 480
#define NBL 6
#define PLANE (NBX * NBY)
#define MAPSZ (PLANE * NBL)
#define EXT 2
#define W 5
#define INV_SQRT2 0.70710678118654752440f
#define INV_CAP 0.0625f

/* ---- spatial tiling: NT = 960, demand block = 512 thr (8 waves) ->
   4 blocks/CU x 8 waves = 32/32 waves, 960 <= 1024 slots: ONE round
   with FULL wave occupancy (R14: 640-thr block wave-capped at 3/CU). ---- */
#define TW 7                     /* tile width in x-bins  (168/7  = 24) */
#define TH 12                    /* tile height in y-bins (480/12 = 40) */
#define TX (NBX / TW)            /* 24 */
#define TY (NBY / TH)            /* 40 */
#define NT (TX * TY)             /* 960 tiles */
#define GPT (TW * TH * NBL)      /* 504 (cell,type) groups per tile */
#define BLOCKD 512               /* 8 waves; ghosts 504..511 */
#define NWAVES (BLOCKD / 64)     /* 8 */
#define LTW (TW + 2 * EXT)       /* 11 */
#define LTH (TH + 2 * EXT)       /* 16 */
#define LTHP 17                  /* odd -> coprime w/ 32 banks */
#define TSTRIDE (LTW * LTHP)     /* 187 */
#define SLABP (NBL * TSTRIDE)    /* 1122 floats = 4.5 KB */
#define SLABPAD 128              /* ghost-safe scratch region */
#define BATCH 544                /* LDS batch: total demand LDS 39.1 KB < 40 KB */
#define WSTR 13                  /* weight-record stride: coprime w/ 32 banks */
#define CAP 2048                 /* payload slots per tile (mean 1042, sd ~32) */
#define WIN 4096                 /* items per k_sort window */
#define SORT_BS 512
#define OUT_BS 512

/* Branch-free erf, Abramowitz-Stegun 7.1.26 (|err| <= 1.5e-7, |x| <= 2.14 here). */
__device__ __forceinline__ float erf_fast(float x) {
    float ax = fabsf(x);
    float t = __builtin_amdgcn_rcpf(fmaf(0.3275911f, ax, 1.0f));
    float p = fmaf(1.061405429f, t, -1.453152027f);
    p = fmaf(p, t, 1.421413741f);
    p = fmaf(p, t, -0.284496736f);
    p = fmaf(p, t, 0.254829592f);
    p = p * t;
    float e = __expf(-ax * ax);
    float r = fmaf(-p, e, 1.0f);
    return copysignf(r, x);
}

/* 5 axis weights (zeroed for out-of-range bins). */
__device__ __forceinline__ void axis_w(float c, int nb, float* g) {
    int b0 = (int)floorf(c);
    float t0 = (float)(b0 - EXT) - c;
    float e[W + 1];
#pragma unroll
    for (int k = 0; k <= W; ++k) e[k] = erf_fast((t0 + (float)k) * INV_SQRT2);
#pragma unroll
    for (int j = 0; j < W; ++j) {
        int b = b0 - EXT + j;
        g[j] = (b >= 0 && b < nb) ? 0.5f * (e[j + 1] - e[j]) : 0.0f;
    }
}

__device__ __forceinline__ int tile_of_xy(float cx, float cy) {
    int bx = (int)floorf(cx); bx = bx < 0 ? 0 : (bx > NBX - 1 ? NBX - 1 : bx);
    int by = (int)floorf(cy); by = by < 0 ? 0 : (by > NBY - 1 ? NBY - 1 : by);
    return (bx / TW) * TY + (by / TH);
}

__device__ __forceinline__ int group_key(float4 p, int x0, int y0) {
    int bx = (int)floorf(p.x) - x0;
    int by = (int)floorf(p.y) - y0;
    bx = bx < 0 ? 0 : (bx > TW - 1 ? TW - 1 : bx);
    by = by < 0 ? 0 : (by > TH - 1 ? TH - 1 : by);
    return (bx * TH + by) * NBL + (__float_as_int(p.w) & 7);
}

/* Pass 1 (fused build+hist+scan+scatter): one 4096-item LDS window per
   block; one global reservation atomic per (window,tile). */
__global__ __launch_bounds__(SORT_BS) void k_sort(
        const float* __restrict__ pos, const float* __restrict__ nsx,
        const float* __restrict__ nsy, const int* __restrict__ idx,
        const int* __restrict__ ltyp,
        int* __restrict__ tileCount, float4* __restrict__ sorted,
        int n, int Linst) {
    __shared__ float4 buf[WIN];
    __shared__ int cnt[NT];
    __shared__ int base[NT];
    int chunk = (Linst + gridDim.x - 1) / gridDim.x;
    int lo = blockIdx.x * chunk;
    int hi = lo + chunk; if (hi > Linst) hi = Linst;
    for (int w0 = lo; w0 < hi; w0 += WIN) {
        int wn = hi - w0; if (wn > WIN) wn = WIN;
        for (int t = threadIdx.x; t < NT; t += blockDim.x) cnt[t] = 0;
        __syncthreads();
        for (int j = threadIdx.x; j < wn; j += blockDim.x) {
            int i = w0 + j;
            int id = idx[i];
            float sx = nsx[id], sy = nsy[id];
            float cx = pos[id] + 0.5f * sx;
            float cy = pos[n + id] + 0.5f * sy;
            buf[j] = make_float4(cx, cy, sx * sy,
                                 __int_as_float((id << 3) | (ltyp[id] & 7)));
            atomicAdd(&cnt[tile_of_xy(cx, cy)], 1);
        }
        __syncthreads();
        for (int t = threadIdx.x; t < NT; t += blockDim.x) {
            base[t] = cnt[t] ? atomicAdd(&tileCount[t], cnt[t]) : 0;
            cnt[t] = 0;                 /* reuse as local cursor */
        }
        __syncthreads();
        for (int j = threadIdx.x; j < wn; j += blockDim.x) {
            float4 p = buf[j];
            int t = tile_of_xy(p.x, p.y);
            int r = base[t] + atomicAdd(&cnt[t], 1);
            if (r < CAP) sorted[(size_t)t * CAP + r] = p;   /* overflow guard */
        }
        __syncthreads();
    }
}

/* Pass 2 (fused subsort+demand): 960 blocks of 512 thr (8 waves), 4/CU ->
   one round at 32/32 waves. Ghost threads 504..511: v=0 always (keys are
   < GPT), and their phased-merge writes go to the dedicated pad region
   past SLABP — address-disjoint from all real groups (fixes the latent
   R13/R14 ghost-vs-real RMW race). */
__global__ __launch_bounds__(BLOCKD) void k_demand3(const float4* __restrict__ sorted,
                                                    const int* __restrict__ tileCount,
                                                    float* __restrict__ slabs) {
    __shared__ float wbuf[BATCH * WSTR];
    __shared__ unsigned short keys[BATCH];
    __shared__ unsigned short order[BATCH];
    __shared__ int h[BLOCKD];
    __shared__ int cur[BLOCKD];
    __shared__ int wsum[NWAVES];
    __shared__ float slab[SLABP + SLABPAD];
    int t = blockIdx.x, tid = threadIdx.x;
    int cntT = tileCount[t]; if (cntT > CAP) cntT = CAP;
    const float4* src = sorted + (size_t)t * CAP;
    int x0 = (t / TY) * TW, y0 = (t % TY) * TH;
    for (int s = tid; s < SLABP + SLABPAD; s += BLOCKD) slab[s] = 0.0f;
    int typ = tid % NBL, lc = tid / NBL;
    int lx = lc / TH, ly = lc % TH;
    bool real = (tid < GPT);
    int lane = tid & 63, wv = tid >> 6;
    float acc[W * W];
#pragma unroll
    for (int k = 0; k < W * W; ++k) acc[k] = 0.0f;

    for (int b = 0; b < cntT; b += BATCH) {
        int cnt = cntT - b; if (cnt > BATCH) cnt = BATCH;
        h[tid] = 0;
        __syncthreads();
        /* phase 1: balanced erf + weight store + hist */
        for (int j = tid; j < cnt; j += BLOCKD) {
            float4 p = src[b + j];
            int key = group_key(p, x0, y0);
            keys[j] = (unsigned short)key;
            float gx[W], gy[W];
            axis_w(p.x, NBX, gx);
            axis_w(p.y, NBY, gy);
            float* wr = &wbuf[j * WSTR];
#pragma unroll
            for (int k = 0; k < W; ++k) wr[k] = gx[k] * p.z;
#pragma unroll
            for (int k = 0; k < W; ++k) wr[W + k] = gy[k];
            atomicAdd(&h[key], 1);
        }
        __syncthreads();
        int v = h[tid];                     /* ghosts: 0 */
        int sc = v;                         /* wave-level inclusive scan */
#pragma unroll
        for (int off = 1; off < 64; off <<= 1) {
            int u = __shfl_up(sc, off);
            if (lane >= off) sc += u;
        }
        if (lane == 63) wsum[wv] = sc;
        __syncthreads();
        int wbase = 0;
        for (int w2 = 0; w2 < wv; ++w2) wbase += wsum[w2];
        int myStart = wbase + sc - v;
        cur[tid] = myStart;
        __syncthreads();
        for (int j = tid; j < cnt; j += BLOCKD) {
            int r = atomicAdd(&cur[(int)keys[j]], 1);
            order[r] = (unsigned short)j;
        }
        __syncthreads();
        /* phase 2: group-gather (divergent but cheap) */
        for (int k = 0; k < v; ++k) {
            const float* wr = &wbuf[(int)order[myStart + k] * WSTR];
            float gxp[W], gy[W];
#pragma unroll
            for (int q = 0; q < W; ++q) gxp[q] = wr[q];
#pragma unroll
            for (int q = 0; q < W; ++q) gy[q] = wr[W + q];
#pragma unroll
            for (int jx = 0; jx < W; ++jx) {
#pragma unroll
                for (int jy = 0; jy < W; ++jy)
                    acc[jx * W + jy] = fmaf(gxp[jx], gy[jy], acc[jx * W + jy]);
            }
        }
        __syncthreads();                    /* wbuf/h reuse fence */
    }

    /* ghosts -> pad region (disjoint from all real addresses) */
    int bse = real ? (typ * TSTRIDE + lx * LTHP + ly) : SLABP;
#pragma unroll
    for (int jx = 0; jx < W; ++jx) {
#pragma unroll
        for (int jy = 0; jy < W; ++jy) {
            __syncthreads();
            slab[bse + jx * LTHP + jy] += acc[jx * W + jy];   /* 0-add ok */
        }
    }
    __syncthreads();
    float* o = slabs + (size_t)t * SLABP;
    for (int s = tid; s < SLABP; s += BLOCKD) o[s] = slab[s];
}

/* Pass 3 (fused compat+gather): 960 blocks of 512 thr, 4/CU -> one round.
   Assemble the tile's compat region in LDS from neighbor slabs + 6x6
   fracture einsum, then one thread per INSTANCE: 12 erfs, 25 LDS reads,
   dot, store. */
__global__ __launch_bounds__(OUT_BS) void k_out3(const float4* __restrict__ sorted,
                                                 const int* __restrict__ tileCount,
                                                 const float* __restrict__ slabs,
                                                 const int* __restrict__ frac,
                                                 float* __restrict__ out) {
    __shared__ float cc[SLABP];
    __shared__ float fr[NBL * NBL];
    int t = blockIdx.x;
    int x0 = (t / TY) * TW, y0 = (t % TY) * TH;
    if (threadIdx.x < NBL * NBL) fr[threadIdx.x] = (float)frac[threadIdx.x];
    __syncthreads();
    for (int s = threadIdx.x; s < LTW * LTH; s += blockDim.x) {
        int lxx = s / LTH, lyy = s % LTH;
        int x = x0 - EXT + lxx, y = y0 - EXT + lyy;
        float d[NBL] = {0, 0, 0, 0, 0, 0};
        if (x >= 0 && x < NBX && y >= 0 && y < NBY) {
            int tx = x / TW, xm = x % TW;
            int ty = y / TH, ym = y % TH;
            int ax0 = (xm < EXT && tx > 0) ? tx - 1 : tx;
            int ax1 = (xm >= TW - EXT && tx < TX - 1) ? tx + 1 : tx;
            int ay0 = (ym < EXT && ty > 0) ? ty - 1 : ty;
            int ay1 = (ym >= TH - EXT && ty < TY - 1) ? ty + 1 : ty;
            for (int ax = ax0; ax <= ax1; ++ax)
                for (int ay = ay0; ay <= ay1; ++ay) {
                    int lx = x - (ax * TW - EXT);
                    int ly = y - (ay * TH - EXT);
                    const float* sl = slabs + (size_t)(ax * TY + ay) * SLABP
                                      + lx * LTHP + ly;
#pragma unroll
                    for (int l = 0; l < NBL; ++l) d[l] += sl[l * TSTRIDE];
                }
        }
#pragma unroll
        for (int tt = 0; tt < NBL; ++tt) {
            float s2 = 0.0f;
#pragma unroll
            for (int l = 0; l < NBL; ++l) s2 += d[l] * fr[tt * NBL + l];
            cc[tt * TSTRIDE + lxx * LTHP + lyy] = s2;
        }
    }
    __syncthreads();
    int cntT = tileCount[t]; if (cntT > CAP) cntT = CAP;
    const float4* src = sorted + (size_t)t * CAP;
    for (int j = threadIdx.x; j < cntT; j += blockDim.x) {
        float4 p = src[j];
        int packed = __float_as_int(p.w);
        int typ = packed & 7;
        float gxw[W], gyw[W];
        axis_w(p.x, NBX, gxw);
        axis_w(p.y, NBY, gyw);
        int lx = (int)floorf(p.x) - x0, ly = (int)floorf(p.y) - y0;
        lx = lx < 0 ? 0 : (lx > TW - 1 ? TW - 1 : lx);
        ly = ly < 0 ? 0 : (ly > TH - 1 ? TH - 1 : ly);
        int base = typ * TSTRIDE + lx * LTHP + ly;
        float sum = 0.0f;
#pragma unroll
        for (int jx = 0; jx < W; ++jx) {
            float row = 0.0f;
#pragma unroll
            for (int jy = 0; jy < W; ++jy)
                row = fmaf(gyw[jy], cc[base + jx * LTHP + jy], row);
            sum = fmaf(gxw[jx], row, sum);
        }
        out[packed >> 3] = sum * INV_CAP;
    }
}

/* ---------- fallback (atomic path) if ws_size is too small ---------- */
__device__ __forceinline__ void axis_frag_fb(float c, int nb, float* g, int* bc) {
    int b0 = (int)floorf(c);
    float t0 = (float)(b0 - EXT) - c;
    float e[W + 1];
#pragma unroll
    for (int k = 0; k <= W; ++k) e[k] = erf_fast((t0 + (float)k) * INV_SQRT2);
#pragma unroll
    for (int j = 0; j < W; ++j) {
        int b = b0 - EXT + j;
        g[j] = (b >= 0 && b < nb) ? 0.5f * (e[j + 1] - e[j]) : 0.0f;
        int bcl = b < 0 ? 0 : b;
        bc[j] = bcl > nb - 1 ? nb - 1 : bcl;
    }
}
__global__ void k_demand_atomic(const float* __restrict__ pos, const float* __restrict__ nsx,
                                const float* __restrict__ nsy, const int* __restrict__ idx,
                                const int* __restrict__ ltyp, float* __restrict__ dem,
                                int n, int Linst) {
    int i = blockIdx.x * blockDim.x + threadIdx.x;
    if (i >= Linst) return;
    int id = idx[i];
    float sx = nsx[id], sy = nsy[id];
    float cx = pos[id] + 0.5f * sx, cy = pos[n + id] + 0.5f * sy;
    float area = sx * sy;
    float gx[W], gy[W]; int bx[W], by[W];
    axis_frag_fb(cx, NBX, gx, bx);
    axis_frag_fb(cy, NBY, gy, by);
    float* plane = dem + ltyp[id] * PLANE;
#pragma unroll
    for (int jx = 0; jx < W; ++jx) {
        float wx = gx[jx] * area;
        if (wx == 0.0f) continue;
        float* row = plane + bx[jx] * NBY;
#pragma unroll
        for (int jy = 0; jy < W; ++jy) {
            float w = wx * gy[jy];
            if (w != 0.0f) atomicAdd(row + by[jy], w);
        }
    }
}
__global__ void k_compat_simple(const float* __restrict__ dem, const int* __restrict__ frac,
                                float* __restrict__ compat) {
    int xy = blockIdx.x * blockDim.x + threadIdx.x;
    if (xy >= PLANE) return;
    float d[NBL];
#pragma unroll
    for (int l = 0; l < NBL; ++l) d[l] = dem[l * PLANE + xy];
#pragma unroll
    for (int t = 0; t < NBL; ++t) {
        float s = 0.0f;
#pragma unroll
        for (int l = 0; l < NBL; ++l) s += d[l] * (float)frac[t * NBL + l];
        compat[t * PLANE + xy] = s;
    }
}
__global__ void k_gather_simple(const float* __restrict__ pos, const float* __restrict__ nsx,
                                const float* __restrict__ nsy, const int* __restrict__ idx,
                                const int* __restrict__ ltyp, const float* __restrict__ compat,
                                float* __restrict__ out, int n, int Linst) {
    int i = blockIdx.x * blockDim.x + threadIdx.x;
    if (i >= Linst) return;
    int id = idx[i];
    float sx = nsx[id], sy = nsy[id];
    float cx = pos[id] + 0.5f * sx, cy = pos[n + id] + 0.5f * sy;
    float gx[W], gy[W]; int bx[W], by[W];
    axis_frag_fb(cx, NBX, gx, bx);
    axis_frag_fb(cy, NBY, gy, by);
    const float* plane = compat + ltyp[id] * PLANE;
    float sum = 0.0f;
#pragma unroll
    for (int jx = 0; jx < W; ++jx) {
        float wx = gx[jx];
        const float* row = plane + bx[jx] * NBY;
#pragma unroll
        for (int jy = 0; jy < W; ++jy) sum += wx * gy[jy] * row[by[jy]];
    }
    out[id] = sum * INV_CAP;
}

extern "C" void kernel_launch(void* const* d_in, const int* in_sizes, int n_in,
                              void* d_out, int out_size, void* d_ws, size_t ws_size,
                              hipStream_t stream) {
    const float* pos  = (const float*)d_in[0];
    const float* nsx  = (const float*)d_in[1];
    const float* nsy  = (const float*)d_in[2];
    const int*   idx  = (const int*)d_in[3];
    const int*   ltyp = (const int*)d_in[4];
    const int*   frac = (const int*)d_in[5];
    int n     = in_sizes[1];
    int Linst = in_sizes[3];
    float* out = (float*)d_out;
    const int bs = 256;

    size_t SBYTES = (size_t)NT * CAP * 16;                 /* slot array ~31.5 MB */
    size_t need = SBYTES
                + (size_t)NT * SLABP * 4                   /* slabs ~4.3 MB */
                + (size_t)NT * 4;                          /* tileCount */

    if (ws_size >= need) {
        char* base = (char*)d_ws;
        float4* sorted  = (float4*)base;
        float* slabs    = (float*)(base + SBYTES);
        int* tileCount  = (int*)(slabs + (size_t)NT * SLABP);

        hipMemsetAsync(tileCount, 0, NT * sizeof(int), stream);
        hipMemsetAsync(out, 0, (size_t)out_size * sizeof(float), stream);

        int sortGrid = (Linst + WIN - 1) / WIN;            /* ~245: one window each */
        k_sort<<<sortGrid, SORT_BS, 0, stream>>>(pos, nsx, nsy, idx, ltyp,
                                                 tileCount, sorted, n, Linst);
        k_demand3<<<NT, BLOCKD, 0, stream>>>(sorted, tileCount, slabs);
        k_out3<<<NT, OUT_BS, 0, stream>>>(sorted, tileCount, slabs, frac, out);
    } else {
        float* dem    = (float*)d_ws;
        float* compat = dem + MAPSZ;
        hipMemsetAsync(dem, 0, MAPSZ * sizeof(float), stream);
        hipMemsetAsync(out, 0, (size_t)out_size * sizeof(float), stream);
        k_demand_atomic<<<(Linst + bs - 1) / bs, bs, 0, stream>>>(pos, nsx, nsy, idx, ltyp, dem, n, Linst);
        k_compat_simple<<<(PLANE + bs - 1) / bs, bs, 0, stream>>>(dem, frac, compat);
        k_gather_simple<<<(Linst + bs - 1) / bs, bs, 0, stream>>>(pos, nsx, nsy, idx, ltyp, compat, out, n, Linst);
    }
}